// Round 4
// baseline (1008.686 us; speedup 1.0000x reference)
//
#include <hip/hip_runtime.h>
#include <hip/hip_bf16.h>

#define NBATCH 16
#define NHEAD  8
#define SEQ    1024
#define EDIM   1024
#define HDIM   128
#define QROWS  8
#define RSQRT_H 0.08838834764831845f   // 1/sqrt(128)

// d_out layout (f32 elems):
//   out0 [16][1024][1024]   @ 0
//   attn [128][1024][1024]  @ 16*1024*1024
// attn replica block j (j=0..7) = attn + j*16M elems; holds rows n=j*16+b (all == P[b]).
// f32 scratch lives inside attn block 2 (67 MB capacity, need 25.7 MB):
//   weff[1024][128] | kx[16][1024][128] | qx[...] | outb[...]
// Order: weff/projx/attn(P->block0, outb->scratch) -> projout -> replicate (clobbers scratch).

// ---------- W_eff[e][h] = sum_j proj_w[e][j*128+h] ----------
__global__ __launch_bounds__(256) void weff_kernel(const float* __restrict__ proj_w,
                                                   float* __restrict__ weff) {
    int i = blockIdx.x * 256 + threadIdx.x;      // 131072 total
    int e = i >> 7, h = i & 127;
    const float* p = proj_w + (size_t)e * (NHEAD * HDIM) + h;
    float s = 0.f;
#pragma unroll
    for (int j = 0; j < NHEAD; ++j) s += p[j * HDIM];
    weff[i] = s;
}

// ---------- OUT[b][s][h] = sum_e X[b][s][e] * W[b%8][e][h] ----------
__global__ __launch_bounds__(256) void projx_kernel(const float* __restrict__ X,
                                                    const float* __restrict__ W,
                                                    float* __restrict__ OUT) {
    const int b  = blockIdx.y;
    const int s0 = blockIdx.x * 64;
    const float* Wh = W + (size_t)(b & 7) * EDIM * HDIM;
    const float* Xb = X + (size_t)b * SEQ * EDIM;
    __shared__ __align__(16) float As[64][17];
    __shared__ __align__(16) float Bs[16][132];
    const int t  = threadIdx.x;
    const int tx = t & 31, tg = t >> 5;
    float acc[8][4];
#pragma unroll
    for (int i = 0; i < 8; ++i)
#pragma unroll
        for (int j = 0; j < 4; ++j) acc[i][j] = 0.f;

    for (int k0 = 0; k0 < EDIM; k0 += 16) {
        {
            int row = t >> 2, col = (t & 3) * 4;
            float4 v = *(const float4*)(Xb + (size_t)(s0 + row) * EDIM + k0 + col);
            As[row][col] = v.x; As[row][col + 1] = v.y;
            As[row][col + 2] = v.z; As[row][col + 3] = v.w;
        }
#pragma unroll
        for (int i = 0; i < 2; ++i) {
            int idx = t + 256 * i;
            int row = idx >> 5, col = (idx & 31) * 4;
            *(float4*)&Bs[row][col] = *(const float4*)(Wh + (size_t)(k0 + row) * HDIM + col);
        }
        __syncthreads();
#pragma unroll
        for (int kk = 0; kk < 16; ++kk) {
            float a[8], bb[4];
#pragma unroll
            for (int i = 0; i < 8; ++i) a[i] = As[tg * 8 + i][kk];
#pragma unroll
            for (int j = 0; j < 4; ++j) bb[j] = Bs[kk][tx + 32 * j];
#pragma unroll
            for (int i = 0; i < 8; ++i)
#pragma unroll
                for (int j = 0; j < 4; ++j) acc[i][j] = fmaf(a[i], bb[j], acc[i][j]);
        }
        __syncthreads();
    }
#pragma unroll
    for (int i = 0; i < 8; ++i) {
        float* o = OUT + (size_t)(b * SEQ + s0 + tg * 8 + i) * HDIM + tx;
#pragma unroll
        for (int j = 0; j < 4; ++j) o[32 * j] = acc[i][j];
    }
}

// ---------- fused attention: one (batch, 8-row q tile) per block ----------
__global__ __launch_bounds__(256) void attn_kernel(const float* __restrict__ kx,
                                                   const float* __restrict__ qxg,
                                                   const int* __restrict__ mlen,
                                                   float* __restrict__ attn0,
                                                   float* __restrict__ outb) {
    __shared__ __align__(16) float Ss[QROWS][1032];
    __shared__ __align__(16) float qxs[QROWS][132];
    __shared__ __align__(16) float kxs[32][132];
    __shared__ float linv[QROWS];
    const int b  = blockIdx.y;
    const int q0 = blockIdx.x * QROWS;
    const int t  = threadIdx.x;
    const int ml = mlen[b];
    const float* kxb = kx + (size_t)b * SEQ * HDIM;

    const int r = t >> 5;     // 0..7
    const int s = t & 31;     // 0..31

    // q tile: 8 rows x 128 cols
    *(float4*)&qxs[r][s * 4] =
        *(const float4*)(qxg + (size_t)(b * SEQ + q0 + r) * HDIM + s * 4);

    // ---- scores: Ss[r][c] = qx[q0+r] . kx[c] ----
    for (int k0 = 0; k0 < SEQ; k0 += 32) {
        __syncthreads();
#pragma unroll
        for (int i = 0; i < 4; ++i) {
            int idx = t + 256 * i;
            int row = idx >> 5, col = (idx & 31) * 4;
            *(float4*)&kxs[row][col] =
                *(const float4*)(kxb + (size_t)(k0 + row) * HDIM + col);
        }
        __syncthreads();
        float acc = 0.f;
        const float* qp = qxs[r];
        const float* kp = kxs[s];
#pragma unroll
        for (int e = 0; e < HDIM; e += 4) {
            float4 qv = *(const float4*)(qp + e);
            float4 kv = *(const float4*)(kp + e);
            acc = fmaf(qv.x, kv.x, acc); acc = fmaf(qv.y, kv.y, acc);
            acc = fmaf(qv.z, kv.z, acc); acc = fmaf(qv.w, kv.w, acc);
        }
        Ss[r][k0 + s] = acc;
    }
    __syncthreads();

    // ---- masked softmax (row r by its 32 lanes) ----
    float m = -3.0e38f;
    float* Sr = Ss[r];
    for (int j = s; j < SEQ; j += 32) {
        float v = Sr[j] * RSQRT_H;
        v = (j < ml) ? v : -10000.0f;
        Sr[j] = v;
        m = fmaxf(m, v);
    }
#pragma unroll
    for (int d = 1; d < 32; d <<= 1) m = fmaxf(m, __shfl_xor(m, d));
    float l = 0.f;
    for (int j = s; j < SEQ; j += 32) {
        float p = __expf(Sr[j] - m);
        Sr[j] = p;                        // unnormalized
        l += p;
    }
#pragma unroll
    for (int d = 1; d < 32; d <<= 1) l += __shfl_xor(l, d);
    if (s == 0) linv[r] = 1.0f / l;
    __syncthreads();

    // ---- write canonical P (f32) into replica block 0 ----
    {
        float* ab = attn0 + (size_t)b * SEQ * SEQ + (size_t)q0 * SEQ;
#pragma unroll
        for (int i = 0; i < 8; ++i) {
            int idx = t + 256 * i;        // 0..2047 float4 index
            int row = idx >> 8;           // 0..7   (256 float4 per row)
            int col = (idx & 255) * 4;    // 0..1020
            float li2 = linv[row];
            float4 pv;
            pv.x = Ss[row][col]     * li2;
            pv.y = Ss[row][col + 1] * li2;
            pv.z = Ss[row][col + 2] * li2;
            pv.w = Ss[row][col + 3] * li2;
            *(float4*)(ab + (size_t)row * SEQ + col) = pv;
        }
    }

    // ---- PV: outb[q0+r][h] = (sum_c P[r][c] * kx[c][h]) * linv[r] ----
    float acc[4] = {0.f, 0.f, 0.f, 0.f};
    for (int k0 = 0; k0 < SEQ; k0 += 32) {
        __syncthreads();
#pragma unroll
        for (int i = 0; i < 4; ++i) {
            int idx = t + 256 * i;
            int row = idx >> 5, col = (idx & 31) * 4;
            *(float4*)&kxs[row][col] =
                *(const float4*)(kxb + (size_t)(k0 + row) * HDIM + col);
        }
        __syncthreads();
#pragma unroll
        for (int kk = 0; kk < 32; ++kk) {
            float p = Ss[r][k0 + kk];
#pragma unroll
            for (int j = 0; j < 4; ++j)
                acc[j] = fmaf(p, kxs[kk][s + 32 * j], acc[j]);
        }
    }
    {
        float li2 = linv[r];
        float* o = outb + (size_t)(b * SEQ + q0 + r) * HDIM + s;
#pragma unroll
        for (int j = 0; j < 4; ++j) o[32 * j] = acc[j] * li2;
    }
}

// ---------- out[b][q][e] = proj_b[e] + sum_h outb[b][q][h] * weff[e][h] ----------
__global__ __launch_bounds__(256) void projout_kernel(const float* __restrict__ outb,
                                                      const float* __restrict__ weff,
                                                      const float* __restrict__ proj_b,
                                                      float* __restrict__ out) {
    const int b  = blockIdx.z;
    const int q0 = blockIdx.x * 32;
    const int e0 = blockIdx.y * 64;
    __shared__ __align__(16) float As[32][133];
    __shared__ __align__(16) float Ws[64][129];
    const int t = threadIdx.x;
#pragma unroll
    for (int i = 0; i < 4; ++i) {
        int idx = t + 256 * i;
        int row = idx >> 5, col = (idx & 31) * 4;
        float4 v = *(const float4*)(outb + (size_t)(b * SEQ + q0 + row) * HDIM + col);
        As[row][col] = v.x; As[row][col + 1] = v.y;
        As[row][col + 2] = v.z; As[row][col + 3] = v.w;
    }
#pragma unroll
    for (int i = 0; i < 8; ++i) {
        int idx = t + 256 * i;
        int row = idx >> 5, col = (idx & 31) * 4;
        float4 v = *(const float4*)(weff + (size_t)(e0 + row) * HDIM + col);
        Ws[row][col] = v.x; Ws[row][col + 1] = v.y;
        Ws[row][col + 2] = v.z; Ws[row][col + 3] = v.w;
    }
    __syncthreads();
    const int rg = t >> 5, tx = t & 31;
    float acc[4][2];
#pragma unroll
    for (int i = 0; i < 4; ++i) { acc[i][0] = 0.f; acc[i][1] = 0.f; }
#pragma unroll 8
    for (int h = 0; h < HDIM; ++h) {
        float a[4], w[2];
#pragma unroll
        for (int i = 0; i < 4; ++i) a[i] = As[rg * 4 + i][h];
#pragma unroll
        for (int j = 0; j < 2; ++j) w[j] = Ws[tx + 32 * j][h];
#pragma unroll
        for (int i = 0; i < 4; ++i)
#pragma unroll
            for (int j = 0; j < 2; ++j) acc[i][j] = fmaf(a[i], w[j], acc[i][j]);
    }
#pragma unroll
    for (int i = 0; i < 4; ++i) {
        size_t rowoff = (size_t)(b * SEQ + q0 + rg * 4 + i) * EDIM + e0 + tx;
#pragma unroll
        for (int j = 0; j < 2; ++j)
            out[rowoff + 32 * j] = acc[i][j] + proj_b[e0 + tx + 32 * j];
    }
}

// ---------- replicate attn block 0 -> blocks 1..7 (16 B vectors) ----------
__global__ __launch_bounds__(256) void replicate_kernel(const uint4* __restrict__ src,
                                                        uint4* __restrict__ dst) {
    size_t i = (size_t)blockIdx.x * 256 + threadIdx.x;   // 0 .. 7*2^22-1
    size_t j = (i >> 22) + 1;                            // 1..7
    size_t off = i & ((1u << 22) - 1);                   // uint4 index within block
    dst[j * 4194304 + off] = src[off];
}

extern "C" void kernel_launch(void* const* d_in, const int* in_sizes, int n_in,
                              void* d_out, int out_size, void* d_ws, size_t ws_size,
                              hipStream_t stream) {
    const float* k      = (const float*)d_in[0];
    const float* q      = (const float*)d_in[1];
    const float* w_kx   = (const float*)d_in[2];
    const float* w_qx   = (const float*)d_in[3];
    const float* proj_w = (const float*)d_in[4];
    const float* proj_b = (const float*)d_in[5];
    const int*   mlen   = (const int*)d_in[6];

    float* out0     = (float*)d_out;
    float* attn_out = out0 + (size_t)NBATCH * SEQ * EDIM;
    const size_t BLK = (size_t)NBATCH * SEQ * SEQ;       // 16,777,216 f32 per replica

    // f32 scratch inside attn replica block 2 (67 MB capacity; rewritten by replicate)
    float* scratch = attn_out + 2 * BLK;
    float* weff = scratch;                 // 131072
    float* kx   = weff + 131072;           // 2097152
    float* qx   = kx + 2097152;            // 2097152
    float* outb = qx + 2097152;            // 2097152  (total 25.7 MB)

    weff_kernel<<<512, 256, 0, stream>>>(proj_w, weff);
    projx_kernel<<<dim3(16, 16), 256, 0, stream>>>(k, w_kx, kx);
    projx_kernel<<<dim3(16, 16), 256, 0, stream>>>(q, w_qx, qx);
    attn_kernel<<<dim3(SEQ / QROWS, NBATCH), 256, 0, stream>>>(kx, qx, mlen, attn_out, outb);
    projout_kernel<<<dim3(32, 16, 16), 256, 0, stream>>>(outb, weff, proj_b, out0);
    replicate_kernel<<<7 * 4194304 / 256, 256, 0, stream>>>((const uint4*)attn_out,
                                                            (uint4*)attn_out);
}

// Round 5
// 378.952 us; speedup vs baseline: 2.6618x; 2.6618x over previous
//
#include <hip/hip_runtime.h>
#include <hip/hip_bf16.h>

#define NBATCH 16
#define SEQ    1024
#define EDIM   1024
#define HDIM   128
#define RSQRT_H 0.08838834764831845f   // 1/sqrt(128)

// d_out layout (f32): out0[16][1024][1024] | attn[128][1024][1024] (8 replica blocks of 16)
// Scratch lives in attn replica block 2 (67.1 MB), clobbered last by replicate:
//   wkT[8][128][1024]bf16 | wqT[...] | weffb[1024][128]bf16 | qxh[16][1024][128]bf16
//   | kxh[...] | kxT[16][128][1024]bf16 | Pb[16][1024][1024]bf16 | outb[16][1024][128]f32

typedef short s8b __attribute__((ext_vector_type(8)));
typedef float f32x4 __attribute__((ext_vector_type(4)));

__device__ __forceinline__ unsigned short bfr(float f) {   // f32 -> bf16 bits, RNE
    unsigned u = __float_as_uint(f);
    u += 0x7fffu + ((u >> 16) & 1u);
    return (unsigned short)(u >> 16);
}

__device__ __forceinline__ f32x4 MFMA(s8b a, s8b b, f32x4 c) {
    return __builtin_amdgcn_mfma_f32_16x16x32_bf16(a, b, c, 0, 0, 0);
}

// ---------- generic 64x64-tile bf16 MFMA GEMM ----------
// A: [M][K] (bf16 or f32, K contiguous). B: [N][K] bf16 (K contiguous; i.e. B^T storage).
// C[m][n] = sum_k A[m][k]*B[n][k] (+bias[n] for MODE 3).
// MODE 0: bf16 A -> f32 C   (score)
// MODE 1: f32  A -> bf16 C  (projx)
// MODE 2: bf16 A -> f32 C   (pv)
// MODE 3: f32  A -> f32 C + bias (projout)
template <int MODE>
__global__ __launch_bounds__(256) void gemm_mfma(
        const void* __restrict__ Ap, const unsigned short* __restrict__ Bp,
        void* __restrict__ Cp, const float* __restrict__ bias,
        int lda, int ldb, int ldc, int K,
        long long saA, long long saB, long long saC, int bmask) {
    const int b  = blockIdx.z;
    const int bm = blockIdx.x * 64, bn = blockIdx.y * 64;
    const int lane = threadIdx.x & 63, w = threadIdx.x >> 6;
    const int wm = (w >> 1) * 32, wn = (w & 1) * 32;
    const int r  = lane & 15, ko = (lane >> 4) * 8;

    const unsigned short* Bb = Bp + (long long)(b & bmask) * saB
                                  + (size_t)(bn + wn + r) * ldb + ko;
    f32x4 acc[2][2] = {};

    if (MODE == 1 || MODE == 3) {
        const float* Ab = (const float*)Ap + (long long)b * saA
                          + (size_t)(bm + wm + r) * lda + ko;
        for (int k = 0; k < K; k += 32) {
            s8b a0, a1;
            float4 u0 = *(const float4*)(Ab + k);
            float4 u1 = *(const float4*)(Ab + k + 4);
            a0[0]=(short)bfr(u0.x); a0[1]=(short)bfr(u0.y);
            a0[2]=(short)bfr(u0.z); a0[3]=(short)bfr(u0.w);
            a0[4]=(short)bfr(u1.x); a0[5]=(short)bfr(u1.y);
            a0[6]=(short)bfr(u1.z); a0[7]=(short)bfr(u1.w);
            float4 v0 = *(const float4*)(Ab + (size_t)16 * lda + k);
            float4 v1 = *(const float4*)(Ab + (size_t)16 * lda + k + 4);
            a1[0]=(short)bfr(v0.x); a1[1]=(short)bfr(v0.y);
            a1[2]=(short)bfr(v0.z); a1[3]=(short)bfr(v0.w);
            a1[4]=(short)bfr(v1.x); a1[5]=(short)bfr(v1.y);
            a1[6]=(short)bfr(v1.z); a1[7]=(short)bfr(v1.w);
            s8b b0 = *(const s8b*)(Bb + k);
            s8b b1 = *(const s8b*)(Bb + (size_t)16 * ldb + k);
            acc[0][0] = MFMA(a0, b0, acc[0][0]);
            acc[0][1] = MFMA(a0, b1, acc[0][1]);
            acc[1][0] = MFMA(a1, b0, acc[1][0]);
            acc[1][1] = MFMA(a1, b1, acc[1][1]);
        }
    } else {
        const unsigned short* Ab = (const unsigned short*)Ap + (long long)b * saA
                                   + (size_t)(bm + wm + r) * lda + ko;
        for (int k = 0; k < K; k += 32) {
            s8b a0 = *(const s8b*)(Ab + k);
            s8b a1 = *(const s8b*)(Ab + (size_t)16 * lda + k);
            s8b b0 = *(const s8b*)(Bb + k);
            s8b b1 = *(const s8b*)(Bb + (size_t)16 * ldb + k);
            acc[0][0] = MFMA(a0, b0, acc[0][0]);
            acc[0][1] = MFMA(a0, b1, acc[0][1]);
            acc[1][0] = MFMA(a1, b0, acc[1][0]);
            acc[1][1] = MFMA(a1, b1, acc[1][1]);
        }
    }

#pragma unroll
    for (int i = 0; i < 2; ++i)
#pragma unroll
    for (int j = 0; j < 2; ++j) {
        const int row0 = bm + wm + i * 16 + (lane >> 4) * 4;
        const int col  = bn + wn + j * 16 + (lane & 15);
        float bv = 0.f;
        if (MODE == 3) bv = bias[col];
#pragma unroll
        for (int jj = 0; jj < 4; ++jj) {
            size_t off = (size_t)((long long)b * saC) + (size_t)(row0 + jj) * ldc + col;
            float v = acc[i][j][jj] + bv;
            if (MODE == 1) ((unsigned short*)Cp)[off] = bfr(v);
            else           ((float*)Cp)[off] = v;
        }
    }
}

// ---------- W_eff[e][h] = sum_j proj_w[e][j*128+h]  (bf16 out) ----------
__global__ __launch_bounds__(256) void weff_kernel(const float* __restrict__ proj_w,
                                                   unsigned short* __restrict__ weffb) {
    int i = blockIdx.x * 256 + threadIdx.x;      // 131072
    int e = i >> 7, h = i & 127;
    const float* p = proj_w + (size_t)e * (8 * HDIM) + h;
    float s = 0.f;
#pragma unroll
    for (int j = 0; j < 8; ++j) s += p[j * HDIM];
    weffb[i] = bfr(s);
}

// ---------- w [8][1024(e)][128(h)] f32 -> wT [8][128(h)][1024(e)] bf16 ----------
__global__ __launch_bounds__(256) void wt_kernel(const float* __restrict__ src,
                                                 unsigned short* __restrict__ dst) {
    __shared__ unsigned short tile[32][40];
    const int hd = blockIdx.z, e0 = blockIdx.x * 32, h0 = blockIdx.y * 32;
    const int t = threadIdx.x, r = t >> 3, c = (t & 7) * 4;
    float4 v = *(const float4*)(src + ((size_t)hd * 1024 + e0 + r) * 128 + h0 + c);
    tile[r][c]     = bfr(v.x);
    tile[r][c + 1] = bfr(v.y);
    tile[r][c + 2] = bfr(v.z);
    tile[r][c + 3] = bfr(v.w);
    __syncthreads();
    ushort4 o;
    o.x = tile[c][r]; o.y = tile[c + 1][r]; o.z = tile[c + 2][r]; o.w = tile[c + 3][r];
    *(ushort4*)(dst + ((size_t)hd * 128 + h0 + r) * 1024 + e0 + c) = o;
}

// ---------- kxh [16][1024][128] bf16 -> kxT [16][128][1024] bf16 ----------
__global__ __launch_bounds__(256) void kxt_kernel(const unsigned short* __restrict__ src,
                                                  unsigned short* __restrict__ dst) {
    __shared__ unsigned short tile[32][40];
    const int b = blockIdx.z, s0 = blockIdx.x * 32, h0 = blockIdx.y * 32;
    const int t = threadIdx.x, r = t >> 3, c = (t & 7) * 4;
    *(ushort4*)&tile[r][c] =
        *(const ushort4*)(src + ((size_t)b * 1024 + s0 + r) * 128 + h0 + c);
    __syncthreads();
    ushort4 o;
    o.x = tile[c][r]; o.y = tile[c + 1][r]; o.z = tile[c + 2][r]; o.w = tile[c + 3][r];
    *(ushort4*)(dst + ((size_t)b * 128 + h0 + r) * 1024 + s0 + c) = o;
}

// ---------- masked softmax over S rows (in place, f32) + bf16 copy ----------
__global__ __launch_bounds__(256) void softmax_kernel(float* __restrict__ S,
                                                      unsigned short* __restrict__ Pb,
                                                      const int* __restrict__ mlen) {
    const int row  = blockIdx.x * 4 + (threadIdx.x >> 6);   // 0..16383
    const int lane = threadIdx.x & 63;
    const int ml   = mlen[row >> 10];
    float* Sr = S + (size_t)row * 1024;
    float v[16];
#pragma unroll
    for (int i = 0; i < 4; ++i) {
        float4 x = *(const float4*)(Sr + lane * 4 + 256 * i);
        v[4 * i] = x.x; v[4 * i + 1] = x.y; v[4 * i + 2] = x.z; v[4 * i + 3] = x.w;
    }
    float m = -3.0e38f;
#pragma unroll
    for (int i = 0; i < 16; ++i) {
        int col = lane * 4 + (i >> 2) * 256 + (i & 3);
        float x = v[i] * RSQRT_H;
        x = (col < ml) ? x : -10000.0f;
        v[i] = x;
        m = fmaxf(m, x);
    }
#pragma unroll
    for (int d = 1; d < 64; d <<= 1) m = fmaxf(m, __shfl_xor(m, d));
    float l = 0.f;
#pragma unroll
    for (int i = 0; i < 16; ++i) { v[i] = __expf(v[i] - m); l += v[i]; }
#pragma unroll
    for (int d = 1; d < 64; d <<= 1) l += __shfl_xor(l, d);
    const float li = 1.0f / l;
#pragma unroll
    for (int i = 0; i < 4; ++i) {
        float4 x;
        x.x = v[4 * i] * li; x.y = v[4 * i + 1] * li;
        x.z = v[4 * i + 2] * li; x.w = v[4 * i + 3] * li;
        *(float4*)(Sr + lane * 4 + 256 * i) = x;
        uint2 pk;
        pk.x = (unsigned)bfr(x.x) | ((unsigned)bfr(x.y) << 16);
        pk.y = (unsigned)bfr(x.z) | ((unsigned)bfr(x.w) << 16);
        *(uint2*)(Pb + (size_t)row * 1024 + lane * 4 + 256 * i) = pk;
    }
}

// ---------- replicate attn block 0 -> blocks 1..7 (read once, write 7) ----------
__global__ __launch_bounds__(256) void replicate_kernel(const uint4* __restrict__ src,
                                                        uint4* __restrict__ dst) {
    size_t off = (size_t)blockIdx.x * 256 + threadIdx.x;   // 0..4194303 (uint4)
    uint4 v = src[off];
#pragma unroll
    for (int j = 1; j < 8; ++j) dst[(size_t)j * 4194304 + off] = v;
}

extern "C" void kernel_launch(void* const* d_in, const int* in_sizes, int n_in,
                              void* d_out, int out_size, void* d_ws, size_t ws_size,
                              hipStream_t stream) {
    const float* k      = (const float*)d_in[0];
    const float* q      = (const float*)d_in[1];
    const float* w_kx   = (const float*)d_in[2];
    const float* w_qx   = (const float*)d_in[3];
    const float* proj_w = (const float*)d_in[4];
    const float* proj_b = (const float*)d_in[5];
    const int*   mlen   = (const int*)d_in[6];

    float* out0  = (float*)d_out;
    float* attn0 = out0 + (size_t)NBATCH * SEQ * EDIM;          // replica block 0
    const size_t BLK = (size_t)NBATCH * SEQ * SEQ;              // 16,777,216 f32

    // scratch inside attn replica block 2
    unsigned short* sc16 = (unsigned short*)(attn0 + 2 * BLK);
    unsigned short* wkT   = sc16;                    // 1,048,576
    unsigned short* wqT   = wkT + 1048576;           // 1,048,576
    unsigned short* weffb = wqT + 1048576;           //   131,072
    unsigned short* qxh   = weffb + 131072;          // 2,097,152
    unsigned short* kxh   = qxh + 2097152;           // 2,097,152
    unsigned short* kxT   = kxh + 2097152;           // 2,097,152
    unsigned short* Pb    = kxT + 2097152;           // 16,777,216
    float*          outb  = (float*)(Pb + 16777216); // 2,097,152 f32   (59 MB total)

    weff_kernel<<<512, 256, 0, stream>>>(proj_w, weffb);
    wt_kernel<<<dim3(32, 4, 8), 256, 0, stream>>>(w_kx, wkT);
    wt_kernel<<<dim3(32, 4, 8), 256, 0, stream>>>(w_qx, wqT);

    // kxh = k @ w_kx[b%8], qxh = q @ w_qx[b%8]   (M=1024,N=128,K=1024)
    gemm_mfma<1><<<dim3(16, 2, 16), 256, 0, stream>>>(
        k, wkT, kxh, nullptr, 1024, 1024, 128, 1024,
        (long long)1024 * 1024, (long long)128 * 1024, (long long)1024 * 128, 7);
    gemm_mfma<1><<<dim3(16, 2, 16), 256, 0, stream>>>(
        q, wqT, qxh, nullptr, 1024, 1024, 128, 1024,
        (long long)1024 * 1024, (long long)128 * 1024, (long long)1024 * 128, 7);

    kxt_kernel<<<dim3(32, 4, 16), 256, 0, stream>>>(kxh, kxT);

    // S = qx @ kx^T  (M=1024,N=1024,K=128) -> attn block 0 (f32)
    gemm_mfma<0><<<dim3(16, 16, 16), 256, 0, stream>>>(
        qxh, kxh, attn0, nullptr, 128, 128, 1024, 128,
        (long long)1024 * 128, (long long)1024 * 128, (long long)1024 * 1024, 15);

    softmax_kernel<<<4096, 256, 0, stream>>>(attn0, Pb, mlen);

    // outb = P @ kx  (M=1024,N=128,K=1024)
    gemm_mfma<2><<<dim3(16, 2, 16), 256, 0, stream>>>(
        Pb, kxT, outb, nullptr, 1024, 1024, 128, 1024,
        (long long)1024 * 1024, (long long)128 * 1024, (long long)1024 * 128, 15);

    // out0 = outb @ weff^T + proj_b  (M=1024,N=1024,K=128)
    gemm_mfma<3><<<dim3(16, 16, 16), 256, 0, stream>>>(
        outb, weffb, out0, proj_b, 128, 128, 1024, 128,
        (long long)1024 * 128, 0, (long long)1024 * 1024, 0);

    replicate_kernel<<<16384, 256, 0, stream>>>((const uint4*)attn0, (uint4*)attn0);
}

// Round 6
// 359.830 us; speedup vs baseline: 2.8032x; 1.0531x over previous
//
#include <hip/hip_runtime.h>
#include <hip/hip_bf16.h>

#define NBATCH 16
#define SEQ    1024
#define EDIM   1024
#define HDIM   128
#define RSQRT_H 0.08838834764831845f   // 1/sqrt(128)

// d_out layout (f32): out0[16][1024][1024] | attn[128][1024][1024] (8 replica blocks of 16)
// Scratch (25.4 MB) lives at the START of attn replica block 2 (batch-slices 0..6.06):
//   wkT[8][128][1024]bf16 | wqT | weffb[1024][128]bf16 | qxh[16][1024][128]bf16 | kxh
//   | kxT[16][128][1024]bf16 | outb[16][1024][128]f32
// fused_attn writes replica blocks {0,1,3..7} always, block 2 only for b>=7 (no overlap
// with scratch). After projout consumes scratch, fixup copies block0 slices 0..6 -> block2.

typedef short s8b __attribute__((ext_vector_type(8)));
typedef float f32x4 __attribute__((ext_vector_type(4)));

__device__ __forceinline__ unsigned short bfr(float f) {   // f32 -> bf16 bits, RNE
    unsigned u = __float_as_uint(f);
    u += 0x7fffu + ((u >> 16) & 1u);
    return (unsigned short)(u >> 16);
}

__device__ __forceinline__ f32x4 MFMA(s8b a, s8b b, f32x4 c) {
    return __builtin_amdgcn_mfma_f32_16x16x32_bf16(a, b, c, 0, 0, 0);
}

// ---------- generic 64x64-tile bf16 MFMA GEMM (modes 1,3 used) ----------
// A: [M][K]. B: [N][K] bf16. C[m][n] = sum_k A[m][k]*B[n][k] (+bias[n] MODE 3).
// MODE 1: f32 A -> bf16 C (projx);  MODE 3: f32 A -> f32 C + bias (projout)
template <int MODE>
__global__ __launch_bounds__(256) void gemm_mfma(
        const void* __restrict__ Ap, const unsigned short* __restrict__ Bp,
        void* __restrict__ Cp, const float* __restrict__ bias,
        int lda, int ldb, int ldc, int K,
        long long saA, long long saB, long long saC, int bmask) {
    const int b  = blockIdx.z;
    const int bm = blockIdx.x * 64, bn = blockIdx.y * 64;
    const int lane = threadIdx.x & 63, w = threadIdx.x >> 6;
    const int wm = (w >> 1) * 32, wn = (w & 1) * 32;
    const int r  = lane & 15, ko = (lane >> 4) * 8;

    const unsigned short* Bb = Bp + (long long)(b & bmask) * saB
                                  + (size_t)(bn + wn + r) * ldb + ko;
    f32x4 acc[2][2] = {};

    const float* Ab = (const float*)Ap + (long long)b * saA
                      + (size_t)(bm + wm + r) * lda + ko;
    for (int k = 0; k < K; k += 32) {
        s8b a0, a1;
        float4 u0 = *(const float4*)(Ab + k);
        float4 u1 = *(const float4*)(Ab + k + 4);
        a0[0]=(short)bfr(u0.x); a0[1]=(short)bfr(u0.y);
        a0[2]=(short)bfr(u0.z); a0[3]=(short)bfr(u0.w);
        a0[4]=(short)bfr(u1.x); a0[5]=(short)bfr(u1.y);
        a0[6]=(short)bfr(u1.z); a0[7]=(short)bfr(u1.w);
        float4 v0 = *(const float4*)(Ab + (size_t)16 * lda + k);
        float4 v1 = *(const float4*)(Ab + (size_t)16 * lda + k + 4);
        a1[0]=(short)bfr(v0.x); a1[1]=(short)bfr(v0.y);
        a1[2]=(short)bfr(v0.z); a1[3]=(short)bfr(v0.w);
        a1[4]=(short)bfr(v1.x); a1[5]=(short)bfr(v1.y);
        a1[6]=(short)bfr(v1.z); a1[7]=(short)bfr(v1.w);
        s8b b0 = *(const s8b*)(Bb + k);
        s8b b1 = *(const s8b*)(Bb + (size_t)16 * ldb + k);
        acc[0][0] = MFMA(a0, b0, acc[0][0]);
        acc[0][1] = MFMA(a0, b1, acc[0][1]);
        acc[1][0] = MFMA(a1, b0, acc[1][0]);
        acc[1][1] = MFMA(a1, b1, acc[1][1]);
    }

#pragma unroll
    for (int i = 0; i < 2; ++i)
#pragma unroll
    for (int j = 0; j < 2; ++j) {
        const int row0 = bm + wm + i * 16 + (lane >> 4) * 4;
        const int col  = bn + wn + j * 16 + (lane & 15);
        float bv = 0.f;
        if (MODE == 3) bv = bias[col];
#pragma unroll
        for (int jj = 0; jj < 4; ++jj) {
            size_t off = (size_t)((long long)b * saC) + (size_t)(row0 + jj) * ldc + col;
            float v = acc[i][j][jj] + bv;
            if (MODE == 1) ((unsigned short*)Cp)[off] = bfr(v);
            else           ((float*)Cp)[off] = v;
        }
    }
}

// ---------- W_eff[e][h] = sum_j proj_w[e][j*128+h]  (bf16 out) ----------
__global__ __launch_bounds__(256) void weff_kernel(const float* __restrict__ proj_w,
                                                   unsigned short* __restrict__ weffb) {
    int i = blockIdx.x * 256 + threadIdx.x;      // 131072
    int e = i >> 7, h = i & 127;
    const float* p = proj_w + (size_t)e * (8 * HDIM) + h;
    float s = 0.f;
#pragma unroll
    for (int j = 0; j < 8; ++j) s += p[j * HDIM];
    weffb[i] = bfr(s);
}

// ---------- w [8][1024(e)][128(h)] f32 -> wT [8][128(h)][1024(e)] bf16 ----------
__global__ __launch_bounds__(256) void wt_kernel(const float* __restrict__ src,
                                                 unsigned short* __restrict__ dst) {
    __shared__ unsigned short tile[32][40];
    const int hd = blockIdx.z, e0 = blockIdx.x * 32, h0 = blockIdx.y * 32;
    const int t = threadIdx.x, r = t >> 3, c = (t & 7) * 4;
    float4 v = *(const float4*)(src + ((size_t)hd * 1024 + e0 + r) * 128 + h0 + c);
    tile[r][c]     = bfr(v.x);
    tile[r][c + 1] = bfr(v.y);
    tile[r][c + 2] = bfr(v.z);
    tile[r][c + 3] = bfr(v.w);
    __syncthreads();
    ushort4 o;
    o.x = tile[c][r]; o.y = tile[c + 1][r]; o.z = tile[c + 2][r]; o.w = tile[c + 3][r];
    *(ushort4*)(dst + ((size_t)hd * 128 + h0 + r) * 1024 + e0 + c) = o;
}

// ---------- kxh [16][1024][128] bf16 -> kxT [16][128][1024] bf16 ----------
__global__ __launch_bounds__(256) void kxt_kernel(const unsigned short* __restrict__ src,
                                                  unsigned short* __restrict__ dst) {
    __shared__ unsigned short tile[32][40];
    const int b = blockIdx.z, s0 = blockIdx.x * 32, h0 = blockIdx.y * 32;
    const int t = threadIdx.x, r = t >> 3, c = (t & 7) * 4;
    *(ushort4*)&tile[r][c] =
        *(const ushort4*)(src + ((size_t)b * 1024 + s0 + r) * 128 + h0 + c);
    __syncthreads();
    ushort4 o;
    o.x = tile[c][r]; o.y = tile[c + 1][r]; o.z = tile[c + 2][r]; o.w = tile[c + 3][r];
    *(ushort4*)(dst + ((size_t)b * 128 + h0 + r) * 1024 + s0 + c) = o;
}

// ---------- fused score+softmax+replica-write+PV: one (batch, 16-row q tile) ----------
__global__ __launch_bounds__(256) void fused_attn(
        const unsigned short* __restrict__ qxh, const unsigned short* __restrict__ kxh,
        const unsigned short* __restrict__ kxT, const int* __restrict__ mlen,
        float* __restrict__ attn0, float* __restrict__ outb) {
    __shared__ __align__(16) float Sf[16][1028];          // 65.8 KB, reused as bf16 P
    unsigned short* Sh = (unsigned short*)&Sf[0][0];      // stride 1032 shorts

    const int b  = blockIdx.y;
    const int q0 = blockIdx.x * 16;
    const int t  = threadIdx.x;
    const int w  = t >> 6, lane = t & 63;
    const int r  = lane & 15, ko4 = lane >> 4, ko = ko4 * 8;
    const int ml = mlen[b];

    // persistent Q fragments (row q0+r, k = kstep*32+ko..+7)
    s8b aq[4];
#pragma unroll
    for (int ks = 0; ks < 4; ++ks)
        aq[ks] = *(const s8b*)(qxh + ((size_t)b * SEQ + q0 + r) * HDIM + ks * 32 + ko);

    // ---- phase 1: scores S[16][1024] via MFMA ----
    for (int nt = w; nt < 64; nt += 4) {
        const int n0 = nt * 16;
        f32x4 acc = {};
#pragma unroll
        for (int ks = 0; ks < 4; ++ks) {
            s8b bk = *(const s8b*)(kxh + ((size_t)b * SEQ + n0 + r) * HDIM + ks * 32 + ko);
            acc = MFMA(aq[ks], bk, acc);
        }
#pragma unroll
        for (int jj = 0; jj < 4; ++jj)
            Sf[ko4 * 4 + jj][n0 + r] = acc[jj];   // D: row=(lane>>4)*4+jj, col=lane&15
    }
    __syncthreads();

    // ---- phase 2: masked softmax (16 lanes per row) + global replica writes ----
    const int rowi = t >> 4, l16 = t & 15;
    float v[64];
#pragma unroll
    for (int i = 0; i < 16; ++i) {
        float4 x = *(const float4*)&Sf[rowi][l16 * 4 + 64 * i];
        v[4 * i] = x.x; v[4 * i + 1] = x.y; v[4 * i + 2] = x.z; v[4 * i + 3] = x.w;
    }
    float m = -3.0e38f;
#pragma unroll
    for (int i = 0; i < 64; ++i) {
        int col = l16 * 4 + 64 * (i >> 2) + (i & 3);
        float x = v[i] * RSQRT_H;
        x = (col < ml) ? x : -10000.0f;
        v[i] = x;
        m = fmaxf(m, x);
    }
#pragma unroll
    for (int d = 1; d < 16; d <<= 1) m = fmaxf(m, __shfl_xor(m, d));
    float l = 0.f;
#pragma unroll
    for (int i = 0; i < 64; ++i) { v[i] = __expf(v[i] - m); l += v[i]; }
#pragma unroll
    for (int d = 1; d < 16; d <<= 1) l += __shfl_xor(l, d);
    const float li = 1.0f / l;

    {
        const size_t base = (size_t)b * SEQ * SEQ + (size_t)(q0 + rowi) * SEQ + l16 * 4;
        const size_t RB = (size_t)NBATCH * SEQ * SEQ;   // 16,777,216
#pragma unroll
        for (int i = 0; i < 16; ++i) {
            float4 y;
            y.x = v[4 * i] * li; y.y = v[4 * i + 1] * li;
            y.z = v[4 * i + 2] * li; y.w = v[4 * i + 3] * li;
            v[4 * i] = y.x; v[4 * i + 1] = y.y; v[4 * i + 2] = y.z; v[4 * i + 3] = y.w;
            float* p0 = attn0 + base + 64 * i;
            *(float4*)(p0)          = y;
            *(float4*)(p0 + RB)     = y;
            if (b >= 7) *(float4*)(p0 + 2 * RB) = y;     // block 2 tail only (scratch!)
            *(float4*)(p0 + 3 * RB) = y;
            *(float4*)(p0 + 4 * RB) = y;
            *(float4*)(p0 + 5 * RB) = y;
            *(float4*)(p0 + 6 * RB) = y;
            *(float4*)(p0 + 7 * RB) = y;
            // bf16 P into LDS (row rowi only touched by this 16-lane group)
            uint2 pk;
            pk.x = (unsigned)bfr(y.x) | ((unsigned)bfr(y.y) << 16);
            pk.y = (unsigned)bfr(y.z) | ((unsigned)bfr(y.w) << 16);
            *(uint2*)(Sh + (size_t)rowi * 1032 + l16 * 4 + 64 * i) = pk;
        }
    }
    __syncthreads();

    // ---- phase 3: PV = P @ kx  (K=1024, N=128) ----
    f32x4 acc2[2] = {};
    for (int ks = 0; ks < 32; ++ks) {
        s8b pa = *(const s8b*)(Sh + (size_t)r * 1032 + ks * 32 + ko);
#pragma unroll
        for (int c = 0; c < 2; ++c) {
            const int n0 = (w * 2 + c) * 16;
            s8b bk = *(const s8b*)(kxT + ((size_t)b * HDIM + n0 + r) * SEQ + ks * 32 + ko);
            acc2[c] = MFMA(pa, bk, acc2[c]);
        }
    }
#pragma unroll
    for (int c = 0; c < 2; ++c) {
        const int n0 = (w * 2 + c) * 16;
#pragma unroll
        for (int jj = 0; jj < 4; ++jj)
            outb[((size_t)b * SEQ + q0 + ko4 * 4 + jj) * HDIM + n0 + r] = acc2[c][jj];
    }
}

// ---------- fixup: copy block0 batch-slices 0..6 -> block2 (covers scratch) ----------
__global__ __launch_bounds__(256) void fixup_kernel(const uint4* __restrict__ src,
                                                    uint4* __restrict__ dst) {
    size_t i = (size_t)blockIdx.x * 256 + threadIdx.x;   // 0 .. 1,835,007
    dst[i] = src[i];
}

extern "C" void kernel_launch(void* const* d_in, const int* in_sizes, int n_in,
                              void* d_out, int out_size, void* d_ws, size_t ws_size,
                              hipStream_t stream) {
    const float* k      = (const float*)d_in[0];
    const float* q      = (const float*)d_in[1];
    const float* w_kx   = (const float*)d_in[2];
    const float* w_qx   = (const float*)d_in[3];
    const float* proj_w = (const float*)d_in[4];
    const float* proj_b = (const float*)d_in[5];
    const int*   mlen   = (const int*)d_in[6];

    float* out0  = (float*)d_out;
    float* attn0 = out0 + (size_t)NBATCH * SEQ * EDIM;          // replica block 0
    const size_t BLK = (size_t)NBATCH * SEQ * SEQ;              // 16,777,216 f32

    // scratch at start of attn replica block 2 (6,356,992 f32 < 7 batch-slices)
    unsigned short* sc16 = (unsigned short*)(attn0 + 2 * BLK);
    unsigned short* wkT   = sc16;                    // 1,048,576 sh
    unsigned short* wqT   = wkT + 1048576;           // 1,048,576
    unsigned short* weffb = wqT + 1048576;           //   131,072
    unsigned short* qxh   = weffb + 131072;          // 2,097,152
    unsigned short* kxh   = qxh + 2097152;           // 2,097,152
    unsigned short* kxT   = kxh + 2097152;           // 2,097,152
    float*          outb  = (float*)(kxT + 2097152); // 2,097,152 f32

    weff_kernel<<<512, 256, 0, stream>>>(proj_w, weffb);
    wt_kernel<<<dim3(32, 4, 8), 256, 0, stream>>>(w_kx, wkT);
    wt_kernel<<<dim3(32, 4, 8), 256, 0, stream>>>(w_qx, wqT);

    // kxh = k @ w_kx[b%8], qxh = q @ w_qx[b%8]   (M=1024,N=128,K=1024)
    gemm_mfma<1><<<dim3(16, 2, 16), 256, 0, stream>>>(
        k, wkT, kxh, nullptr, 1024, 1024, 128, 1024,
        (long long)1024 * 1024, (long long)128 * 1024, (long long)1024 * 128, 7);
    gemm_mfma<1><<<dim3(16, 2, 16), 256, 0, stream>>>(
        q, wqT, qxh, nullptr, 1024, 1024, 128, 1024,
        (long long)1024 * 1024, (long long)128 * 1024, (long long)1024 * 128, 7);

    kxt_kernel<<<dim3(32, 4, 16), 256, 0, stream>>>(kxh, kxT);

    // fused score/softmax/replicas/PV
    fused_attn<<<dim3(64, 16), 256, 0, stream>>>(qxh, kxh, kxT, mlen, attn0, outb);

    // out0 = outb @ weff^T + proj_b  (M=1024,N=1024,K=128)
    gemm_mfma<3><<<dim3(16, 16, 16), 256, 0, stream>>>(
        outb, weffb, out0, proj_b, 128, 128, 1024, 128,
        (long long)1024 * 128, 0, (long long)1024 * 1024, 0);

    // block0 slices 0..6 -> block2 (rewrites scratch region deterministically)
    fixup_kernel<<<7168, 256, 0, stream>>>((const uint4*)attn0,
                                           (uint4*)(attn0 + 2 * BLK));
}

// Round 7
// 311.437 us; speedup vs baseline: 3.2388x; 1.1554x over previous
//
#include <hip/hip_runtime.h>
#include <hip/hip_bf16.h>

#define NBATCH 16
#define SEQ    1024
#define EDIM   1024
#define HDIM   128
#define RSQRT_H 0.08838834764831845f   // 1/sqrt(128)

// d_out layout (f32): out0[16][1024][1024] | attn[128][1024][1024] (8 replica blocks of 16)
// Scratch (25.4 MB = 6.06 batch-slices) at START of attn replica block 2:
//   wkT[8][128][1024]bf16 | wqT | weffb[1024][128]bf16 | qxh[16][1024][128]bf16 | kxh
//   | kxT[16][128][1024]bf16 | outb[16][1024][128]f32
// fused_attn writes replica blocks {0,1,3..7} always, block 2 only for b>=7 (slices 7..15,
// disjoint from scratch). After projout consumes scratch, fixup copies block0 slices 0..6
// -> block2.

typedef short s8b __attribute__((ext_vector_type(8)));
typedef float f32x4 __attribute__((ext_vector_type(4)));

__device__ __forceinline__ unsigned short bfr(float f) {   // f32 -> bf16 bits, RNE
    unsigned u = __float_as_uint(f);
    u += 0x7fffu + ((u >> 16) & 1u);
    return (unsigned short)(u >> 16);
}

__device__ __forceinline__ f32x4 MFMA(s8b a, s8b b, f32x4 c) {
    return __builtin_amdgcn_mfma_f32_16x16x32_bf16(a, b, c, 0, 0, 0);
}

// ---------- projx: OUT[b][s][h] = sum_e X[b][s][e] * W[b%8][e][h], 32x128 tile ----------
// X f32 [16][1024][1024]; WT bf16 [8][128(h)][1024(e)]; OUT bf16 [16][1024][128]
__global__ __launch_bounds__(256) void projx_mfma(const float* __restrict__ X,
                                                  const unsigned short* __restrict__ WT,
                                                  unsigned short* __restrict__ OUT) {
    const int b  = blockIdx.y;
    const int bm = blockIdx.x * 32;
    const int lane = threadIdx.x & 63, w = threadIdx.x >> 6;
    const int wn = w * 32;
    const int r = lane & 15, ko4 = lane >> 4, ko = ko4 * 8;

    const unsigned short* Bb = WT + (size_t)(b & 7) * 131072 + (size_t)(wn + r) * 1024 + ko;
    const float* Ab = X + (size_t)b * 1048576 + (size_t)(bm + r) * 1024 + ko;
    f32x4 acc[2][2] = {};

    for (int k = 0; k < 1024; k += 32) {
        s8b a0, a1;
        float4 u0 = *(const float4*)(Ab + k);
        float4 u1 = *(const float4*)(Ab + k + 4);
        a0[0]=(short)bfr(u0.x); a0[1]=(short)bfr(u0.y);
        a0[2]=(short)bfr(u0.z); a0[3]=(short)bfr(u0.w);
        a0[4]=(short)bfr(u1.x); a0[5]=(short)bfr(u1.y);
        a0[6]=(short)bfr(u1.z); a0[7]=(short)bfr(u1.w);
        float4 v0 = *(const float4*)(Ab + (size_t)16 * 1024 + k);
        float4 v1 = *(const float4*)(Ab + (size_t)16 * 1024 + k + 4);
        a1[0]=(short)bfr(v0.x); a1[1]=(short)bfr(v0.y);
        a1[2]=(short)bfr(v0.z); a1[3]=(short)bfr(v0.w);
        a1[4]=(short)bfr(v1.x); a1[5]=(short)bfr(v1.y);
        a1[6]=(short)bfr(v1.z); a1[7]=(short)bfr(v1.w);
        s8b b0 = *(const s8b*)(Bb + k);
        s8b b1 = *(const s8b*)(Bb + (size_t)16 * 1024 + k);
        acc[0][0] = MFMA(a0, b0, acc[0][0]);
        acc[0][1] = MFMA(a0, b1, acc[0][1]);
        acc[1][0] = MFMA(a1, b0, acc[1][0]);
        acc[1][1] = MFMA(a1, b1, acc[1][1]);
    }
#pragma unroll
    for (int i = 0; i < 2; ++i)
#pragma unroll
    for (int j = 0; j < 2; ++j) {
        const int row0 = bm + i * 16 + ko4 * 4;
        const int col  = wn + j * 16 + r;
#pragma unroll
        for (int jj = 0; jj < 4; ++jj)
            OUT[((size_t)b * SEQ + row0 + jj) * HDIM + col] = bfr(acc[i][j][jj]);
    }
}

// ---------- projout: out[b][q][e] = proj_b[e] + sum_h outb[b][q][h]*weffb[e][h] ----------
__global__ __launch_bounds__(256) void projout_mfma(const float* __restrict__ Ap,
                                                    const unsigned short* __restrict__ Bp,
                                                    float* __restrict__ Cp,
                                                    const float* __restrict__ bias) {
    const int b  = blockIdx.z;
    const int bm = blockIdx.x * 64, bn = blockIdx.y * 64;
    const int lane = threadIdx.x & 63, w = threadIdx.x >> 6;
    const int wm = (w >> 1) * 32, wn = (w & 1) * 32;
    const int r = lane & 15, ko4 = lane >> 4, ko = ko4 * 8;

    const unsigned short* Bb = Bp + (size_t)(bn + wn + r) * HDIM + ko;
    const float* Ab = (const float*)Ap + (size_t)b * SEQ * HDIM
                      + (size_t)(bm + wm + r) * HDIM + ko;
    f32x4 acc[2][2] = {};
    for (int k = 0; k < HDIM; k += 32) {
        s8b a0, a1;
        float4 u0 = *(const float4*)(Ab + k);
        float4 u1 = *(const float4*)(Ab + k + 4);
        a0[0]=(short)bfr(u0.x); a0[1]=(short)bfr(u0.y);
        a0[2]=(short)bfr(u0.z); a0[3]=(short)bfr(u0.w);
        a0[4]=(short)bfr(u1.x); a0[5]=(short)bfr(u1.y);
        a0[6]=(short)bfr(u1.z); a0[7]=(short)bfr(u1.w);
        float4 v0 = *(const float4*)(Ab + (size_t)16 * HDIM + k);
        float4 v1 = *(const float4*)(Ab + (size_t)16 * HDIM + k + 4);
        a1[0]=(short)bfr(v0.x); a1[1]=(short)bfr(v0.y);
        a1[2]=(short)bfr(v0.z); a1[3]=(short)bfr(v0.w);
        a1[4]=(short)bfr(v1.x); a1[5]=(short)bfr(v1.y);
        a1[6]=(short)bfr(v1.z); a1[7]=(short)bfr(v1.w);
        s8b b0 = *(const s8b*)(Bb + k);
        s8b b1 = *(const s8b*)(Bb + (size_t)16 * HDIM + k);
        acc[0][0] = MFMA(a0, b0, acc[0][0]);
        acc[0][1] = MFMA(a0, b1, acc[0][1]);
        acc[1][0] = MFMA(a1, b0, acc[1][0]);
        acc[1][1] = MFMA(a1, b1, acc[1][1]);
    }
#pragma unroll
    for (int i = 0; i < 2; ++i)
#pragma unroll
    for (int j = 0; j < 2; ++j) {
        const int row0 = bm + wm + i * 16 + ko4 * 4;
        const int col  = bn + wn + j * 16 + r;
        const float bv = bias[col];
#pragma unroll
        for (int jj = 0; jj < 4; ++jj)
            Cp[(size_t)b * SEQ * EDIM + (size_t)(row0 + jj) * EDIM + col]
                = acc[i][j][jj] + bv;
    }
}

// ---------- W_eff[e][h] = sum_j proj_w[e][j*128+h]  (bf16 out) ----------
__global__ __launch_bounds__(256) void weff_kernel(const float* __restrict__ proj_w,
                                                   unsigned short* __restrict__ weffb) {
    int i = blockIdx.x * 256 + threadIdx.x;      // 131072
    int e = i >> 7, h = i & 127;
    const float* p = proj_w + (size_t)e * (8 * HDIM) + h;
    float s = 0.f;
#pragma unroll
    for (int j = 0; j < 8; ++j) s += p[j * HDIM];
    weffb[i] = bfr(s);
}

// ---------- w [8][1024(e)][128(h)] f32 -> wT [8][128(h)][1024(e)] bf16 ----------
__global__ __launch_bounds__(256) void wt_kernel(const float* __restrict__ src,
                                                 unsigned short* __restrict__ dst) {
    __shared__ unsigned short tile[32][40];
    const int hd = blockIdx.z, e0 = blockIdx.x * 32, h0 = blockIdx.y * 32;
    const int t = threadIdx.x, r = t >> 3, c = (t & 7) * 4;
    float4 v = *(const float4*)(src + ((size_t)hd * 1024 + e0 + r) * 128 + h0 + c);
    tile[r][c]     = bfr(v.x);
    tile[r][c + 1] = bfr(v.y);
    tile[r][c + 2] = bfr(v.z);
    tile[r][c + 3] = bfr(v.w);
    __syncthreads();
    ushort4 o;
    o.x = tile[c][r]; o.y = tile[c + 1][r]; o.z = tile[c + 2][r]; o.w = tile[c + 3][r];
    *(ushort4*)(dst + ((size_t)hd * 128 + h0 + r) * 1024 + e0 + c) = o;
}

// ---------- kxh [16][1024][128] bf16 -> kxT [16][128][1024] bf16 ----------
__global__ __launch_bounds__(256) void kxt_kernel(const unsigned short* __restrict__ src,
                                                  unsigned short* __restrict__ dst) {
    __shared__ unsigned short tile[32][40];
    const int b = blockIdx.z, s0 = blockIdx.x * 32, h0 = blockIdx.y * 32;
    const int t = threadIdx.x, r = t >> 3, c = (t & 7) * 4;
    *(ushort4*)&tile[r][c] =
        *(const ushort4*)(src + ((size_t)b * 1024 + s0 + r) * 128 + h0 + c);
    __syncthreads();
    ushort4 o;
    o.x = tile[c][r]; o.y = tile[c + 1][r]; o.z = tile[c + 2][r]; o.w = tile[c + 3][r];
    *(ushort4*)(dst + ((size_t)b * 128 + h0 + r) * 1024 + s0 + c) = o;
}

// ---------- fused score+softmax+replica-write+PV, S in registers ----------
__global__ __launch_bounds__(256) void fused_attn(
        const unsigned short* __restrict__ qxh, const unsigned short* __restrict__ kxh,
        const unsigned short* __restrict__ kxT, const int* __restrict__ mlen,
        float* __restrict__ attn0, float* __restrict__ outb) {
    __shared__ unsigned short Ph[16][1048];    // bf16 P, 32.75 KB (stride 2-way-free)
    __shared__ float redm[4][16];
    __shared__ float redl[4][16];

    // XCD-chunk swizzle: dispatch-consecutive blocks (same XCD stride 8) -> same batches
    const int flat = blockIdx.y * 64 + blockIdx.x;         // 0..1023
    const int work = (flat & 7) * 128 + (flat >> 3);       // bijective
    const int b  = work >> 6;
    const int q0 = (work & 63) * 16;

    const int t = threadIdx.x, w = t >> 6, lane = t & 63;
    const int r = lane & 15, ko4 = lane >> 4, ko = ko4 * 8;
    const int ml = mlen[b];

    s8b aq[4];
#pragma unroll
    for (int ks = 0; ks < 4; ++ks)
        aq[ks] = *(const s8b*)(qxh + ((size_t)b * SEQ + q0 + r) * HDIM + ks * 32 + ko);

    // ---- phase 1: scores into registers (wave w owns cols nt=w+4i) ----
    f32x4 sacc[16];
#pragma unroll
    for (int i = 0; i < 16; ++i) {
        const int n0 = (w + 4 * i) * 16;
        f32x4 acc = {};
#pragma unroll
        for (int ks = 0; ks < 4; ++ks) {
            s8b bk = *(const s8b*)(kxh + ((size_t)b * SEQ + n0 + r) * HDIM + ks * 32 + ko);
            acc = MFMA(aq[ks], bk, acc);
        }
        sacc[i] = acc;
    }

    // ---- mask + scale + per-thread partial max (rows ko4*4+jj, cols n0+r) ----
    float pm[4] = {-3.0e38f, -3.0e38f, -3.0e38f, -3.0e38f};
#pragma unroll
    for (int i = 0; i < 16; ++i) {
        const int col = (w + 4 * i) * 16 + r;
#pragma unroll
        for (int jj = 0; jj < 4; ++jj) {
            float x = sacc[i][jj] * RSQRT_H;
            x = (col < ml) ? x : -10000.0f;
            sacc[i][jj] = x;
            pm[jj] = fmaxf(pm[jj], x);
        }
    }
#pragma unroll
    for (int d = 1; d < 16; d <<= 1)
#pragma unroll
        for (int jj = 0; jj < 4; ++jj) pm[jj] = fmaxf(pm[jj], __shfl_xor(pm[jj], d));
    if (r == 0) {
#pragma unroll
        for (int jj = 0; jj < 4; ++jj) redm[w][ko4 * 4 + jj] = pm[jj];
    }
    __syncthreads();
    float m[4];
#pragma unroll
    for (int jj = 0; jj < 4; ++jj) {
        const int row = ko4 * 4 + jj;
        m[jj] = fmaxf(fmaxf(redm[0][row], redm[1][row]),
                      fmaxf(redm[2][row], redm[3][row]));
    }
    float pl[4] = {0.f, 0.f, 0.f, 0.f};
#pragma unroll
    for (int i = 0; i < 16; ++i)
#pragma unroll
        for (int jj = 0; jj < 4; ++jj) {
            float e = __expf(sacc[i][jj] - m[jj]);
            sacc[i][jj] = e;
            pl[jj] += e;
        }
#pragma unroll
    for (int d = 1; d < 16; d <<= 1)
#pragma unroll
        for (int jj = 0; jj < 4; ++jj) pl[jj] += __shfl_xor(pl[jj], d);
    if (r == 0) {
#pragma unroll
        for (int jj = 0; jj < 4; ++jj) redl[w][ko4 * 4 + jj] = pl[jj];
    }
    __syncthreads();
    float li[4];
#pragma unroll
    for (int jj = 0; jj < 4; ++jj) {
        const int row = ko4 * 4 + jj;
        li[jj] = 1.0f / (redl[0][row] + redl[1][row] + redl[2][row] + redl[3][row]);
    }

    // ---- phase 2: normalized P -> 8 replica blocks + bf16 P -> LDS ----
    const size_t RB = (size_t)NBATCH * SEQ * SEQ;
    float* base0 = attn0 + (size_t)b * SEQ * SEQ;
    const bool wr2 = (b >= 7);
#pragma unroll
    for (int i = 0; i < 16; ++i) {
        const int n0 = (w + 4 * i) * 16;
#pragma unroll
        for (int jj = 0; jj < 4; ++jj) {
            const int row = ko4 * 4 + jj;
            const float y = sacc[i][jj] * li[jj];
            const size_t off = (size_t)(q0 + row) * SEQ + n0 + r;
            base0[off]          = y;
            base0[off + RB]     = y;
            base0[off + 3 * RB] = y;
            base0[off + 4 * RB] = y;
            base0[off + 5 * RB] = y;
            base0[off + 6 * RB] = y;
            base0[off + 7 * RB] = y;
            if (wr2) base0[off + 2 * RB] = y;
            Ph[row][n0 + r] = bfr(y);
        }
    }
    __syncthreads();

    // ---- phase 3: PV = P @ kx  (K=1024, N=128) ----
    f32x4 acc2[2] = {};
    for (int ks = 0; ks < 32; ++ks) {
        s8b pa = *(const s8b*)(&Ph[r][ks * 32 + ko]);
#pragma unroll
        for (int c = 0; c < 2; ++c) {
            const int n0 = (w * 2 + c) * 16;
            s8b bk = *(const s8b*)(kxT + ((size_t)b * HDIM + n0 + r) * SEQ + ks * 32 + ko);
            acc2[c] = MFMA(pa, bk, acc2[c]);
        }
    }
#pragma unroll
    for (int c = 0; c < 2; ++c) {
        const int n0 = (w * 2 + c) * 16;
#pragma unroll
        for (int jj = 0; jj < 4; ++jj)
            outb[((size_t)b * SEQ + q0 + ko4 * 4 + jj) * HDIM + n0 + r] = acc2[c][jj];
    }
}

// ---------- fixup: copy block0 batch-slices 0..6 -> block2 (covers scratch) ----------
__global__ __launch_bounds__(256) void fixup_kernel(const uint4* __restrict__ src,
                                                    uint4* __restrict__ dst) {
    size_t i = (size_t)blockIdx.x * 256 + threadIdx.x;   // 0 .. 1,835,007
    dst[i] = src[i];
}

extern "C" void kernel_launch(void* const* d_in, const int* in_sizes, int n_in,
                              void* d_out, int out_size, void* d_ws, size_t ws_size,
                              hipStream_t stream) {
    const float* k      = (const float*)d_in[0];
    const float* q      = (const float*)d_in[1];
    const float* w_kx   = (const float*)d_in[2];
    const float* w_qx   = (const float*)d_in[3];
    const float* proj_w = (const float*)d_in[4];
    const float* proj_b = (const float*)d_in[5];
    const int*   mlen   = (const int*)d_in[6];

    float* out0  = (float*)d_out;
    float* attn0 = out0 + (size_t)NBATCH * SEQ * EDIM;          // replica block 0
    const size_t BLK = (size_t)NBATCH * SEQ * SEQ;              // 16,777,216 f32

    // scratch at start of attn replica block 2 (6,356,992 f32 = 6.06 batch-slices)
    unsigned short* sc16 = (unsigned short*)(attn0 + 2 * BLK);
    unsigned short* wkT   = sc16;                    // 1,048,576 sh
    unsigned short* wqT   = wkT + 1048576;           // 1,048,576
    unsigned short* weffb = wqT + 1048576;           //   131,072
    unsigned short* qxh   = weffb + 131072;          // 2,097,152
    unsigned short* kxh   = qxh + 2097152;           // 2,097,152
    unsigned short* kxT   = kxh + 2097152;           // 2,097,152
    float*          outb  = (float*)(kxT + 2097152); // 2,097,152 f32

    weff_kernel<<<512, 256, 0, stream>>>(proj_w, weffb);
    wt_kernel<<<dim3(32, 4, 8), 256, 0, stream>>>(w_kx, wkT);
    wt_kernel<<<dim3(32, 4, 8), 256, 0, stream>>>(w_qx, wqT);

    projx_mfma<<<dim3(32, 16), 256, 0, stream>>>(k, wkT, kxh);
    projx_mfma<<<dim3(32, 16), 256, 0, stream>>>(q, wqT, qxh);

    kxt_kernel<<<dim3(32, 4, 16), 256, 0, stream>>>(kxh, kxT);

    fused_attn<<<dim3(64, 16), 256, 0, stream>>>(qxh, kxh, kxT, mlen, attn0, outb);

    projout_mfma<<<dim3(16, 16, 16), 256, 0, stream>>>(outb, weffb, out0, proj_b);

    fixup_kernel<<<7168, 256, 0, stream>>>((const uint4*)attn0,
                                           (uint4*)(attn0 + 2 * BLK));
}